// Round 1
// baseline (272.679 us; speedup 1.0000x reference)
//
#include <hip/hip_runtime.h>
#include <math.h>

// Problem constants (fixed by the reference setup)
#define B_ 4
#define N_ 6400
#define D_ 32
#define TILE 256
#define NCH 25   // ceil(N_/TILE)

static constexpr float MARGIN_ = 0.3f;

// ---------------- Kernel 1: compact fg indices + gather + L2-normalize ----------------
// One block per batch. Ballot-based stream compaction preserving index order,
// then gather pred rows for fg anchors, normalize (v / max(||v||, 1e-12)).
__global__ __launch_bounds__(1024) void k_compact(const float* __restrict__ pred,
                                                  const int* __restrict__ gt,
                                                  const int* __restrict__ fg,
                                                  float* __restrict__ coeffs_c,
                                                  int* __restrict__ clist,
                                                  int* __restrict__ cg,
                                                  int* __restrict__ Marr,
                                                  float* __restrict__ accum) {
    int b = blockIdx.x;
    int tid = threadIdx.x;
    if (b == 0 && tid == 0) { accum[0] = 0.0f; ((int*)accum)[1] = 0; }

    __shared__ int wsum[16];
    __shared__ int sbase;
    if (tid == 0) sbase = 0;
    __syncthreads();

    int lane = tid & 63, wv = tid >> 6;
    for (int t0 = 0; t0 < N_; t0 += 1024) {
        int idx = t0 + tid;
        bool flag = (idx < N_) && (fg[b * N_ + idx] != 0);
        unsigned long long mask = __ballot(flag);
        int lp = __popcll(mask & ((1ull << lane) - 1ull));
        if (lane == 0) wsum[wv] = __popcll(mask);
        __syncthreads();
        int woff = 0, btot = 0;
        #pragma unroll
        for (int w = 0; w < 16; ++w) { if (w < wv) woff += wsum[w]; btot += wsum[w]; }
        int base = sbase;
        if (flag) {
            int pos = base + woff + lp;
            clist[b * N_ + pos] = idx;
            cg[b * N_ + pos] = gt[b * N_ + idx];
        }
        __syncthreads();
        if (tid == 0) sbase = base + btot;
        __syncthreads();
    }
    int M = sbase;
    if (tid == 0) Marr[b] = M;

    // Gather + normalize only the compacted (fg) rows.
    for (int r = tid; r < M; r += 1024) {
        int orig = clist[b * N_ + r];
        const float4* s4 = (const float4*)(pred + ((size_t)b * N_ + orig) * D_);
        float4 v[8];
        float ssq = 0.0f;
        #pragma unroll
        for (int k = 0; k < 8; ++k) {
            v[k] = s4[k];
            ssq += v[k].x * v[k].x + v[k].y * v[k].y + v[k].z * v[k].z + v[k].w * v[k].w;
        }
        float nrm = fmaxf(sqrtf(ssq), 1e-12f);
        float4* d4 = (float4*)(coeffs_c + ((size_t)b * N_ + r) * D_);
        #pragma unroll
        for (int k = 0; k < 8; ++k) {
            float4 o;
            o.x = v[k].x / nrm; o.y = v[k].y / nrm; o.z = v[k].z / nrm; o.w = v[k].w / nrm;
            d4[k] = o;
        }
    }
}

// ---------------- Kernel 2: pass over (anchor-tile x m-chunk) ----------------
// grid = (NCH anchor tiles, NCH m-chunks, B). Each thread = one compacted anchor.
// m-chunk (256 rows x 32 f32) staged in LDS; all lanes broadcast-read the same
// c[m] row (conflict-free). Outputs per (anchor, chunk): same-instance count
// (excluding self) and max negative sim.
__global__ __launch_bounds__(256) void k_pass(const float* __restrict__ coeffs_c,
                                              const int* __restrict__ cg,
                                              const int* __restrict__ Marr,
                                              int* __restrict__ p_cnt,
                                              float* __restrict__ p_best) {
    int b = blockIdx.z;
    int M = Marr[b];
    int i0 = blockIdx.x * TILE;
    int j0 = blockIdx.y * TILE;
    if (i0 >= M || j0 >= M) return;   // block-uniform exit

    __shared__ float sc[TILE * D_];
    __shared__ int sg[TILE];
    int tid = threadIdx.x;

    { // stage gt ids (pad = -1: neither pos nor neg)
        int j = j0 + tid;
        sg[tid] = (j < M) ? cg[b * N_ + j] : -1;
    }
    { // stage coeff rows: thread t -> float4 column (t&7), rows (t>>3)+32k
        int col = tid & 7;
        int row0 = tid >> 3;
        #pragma unroll
        for (int k = 0; k < 8; ++k) {
            int row = row0 + 32 * k;
            int j = j0 + row;
            float4 val = make_float4(0.f, 0.f, 0.f, 0.f);
            if (j < M) val = ((const float4*)(coeffs_c + ((size_t)b * N_ + j) * D_))[col];
            ((float4*)sc)[row * 8 + col] = val;
        }
    }
    __syncthreads();

    int i = i0 + tid;
    bool active = (i < M);
    int ga = -2;
    float4 ca[8];
    if (active) {
        const float4* a4 = (const float4*)(coeffs_c + ((size_t)b * N_ + i) * D_);
        #pragma unroll
        for (int k = 0; k < 8; ++k) ca[k] = a4[k];
        ga = cg[b * N_ + i];
    } else {
        #pragma unroll
        for (int k = 0; k < 8; ++k) ca[k] = make_float4(0.f, 0.f, 0.f, 0.f);
    }

    float best = -INFINITY;
    int cnt = 0;
    int jmax = min(TILE, M - j0);
    for (int m = 0; m < jmax; ++m) {
        const float4* cm = (const float4*)(sc + m * D_);
        float a0 = 0.f, a1 = 0.f, a2 = 0.f, a3 = 0.f;
        #pragma unroll
        for (int k = 0; k < 8; ++k) {
            float4 x = cm[k];
            a0 = fmaf(ca[k].x, x.x, a0);
            a1 = fmaf(ca[k].y, x.y, a1);
            a2 = fmaf(ca[k].z, x.z, a2);
            a3 = fmaf(ca[k].w, x.w, a3);
        }
        float s = (a0 + a1) + (a2 + a3);
        int g = sg[m];
        bool same = (g == ga);
        bool isneg = (!same) && (g >= 0);
        if (isneg && s > best) best = s;
        cnt += (same && (j0 + m != i)) ? 1 : 0;
    }

    if (active) {
        int pidx = (b * N_ + i) * NCH + blockIdx.y;
        p_cnt[pidx] = cnt;
        p_best[pidx] = best;
    }
}

// ---------------- Kernel 3: combine partials, pick random positive, hinge ----------------
__global__ __launch_bounds__(256) void k_combine(const float* __restrict__ coeffs_c,
                                                 const int* __restrict__ cg,
                                                 const int* __restrict__ clist,
                                                 const int* __restrict__ Marr,
                                                 const float* __restrict__ pos_rand,
                                                 const int* __restrict__ p_cnt,
                                                 const float* __restrict__ p_best,
                                                 float* __restrict__ accum) {
    int b = blockIdx.y;
    int M = Marr[b];
    int i0 = blockIdx.x * TILE;
    if (i0 >= M) return;  // block-uniform

    int tid = threadIdx.x;
    int i = i0 + tid;
    float contrib = 0.0f;
    int vflag = 0;

    if (i < M) {
        int nch = (M + TILE - 1) / TILE;
        int base = (b * N_ + i) * NCH;
        int num_pos = 0;
        float best = -INFINITY;
        for (int s = 0; s < nch; ++s) {
            num_pos += p_cnt[base + s];
            float v = p_best[base + s];
            if (v > best) best = v;
        }
        bool hasneg = (best > -1e37f);
        if (num_pos >= 1 && hasneg) {
            int orig = clist[b * N_ + i];
            float u = pos_rand[b * N_ + orig];
            int pc = (int)floorf(u * (float)num_pos);   // matches jnp float32 math
            int hi = num_pos - 1;
            pc = pc < 0 ? 0 : (pc > hi ? hi : pc);
            int target = pc + 1;
            // locate chunk holding the target-th positive
            int s = 0, c0 = 0;
            for (; s < nch; ++s) { int c = p_cnt[base + s]; if (c0 + c >= target) break; c0 += c; }
            int need = target - c0;
            int jstart = s * TILE, jend = min(jstart + TILE, M);
            int ga = cg[b * N_ + i];
            int posj = -1;
            for (int j = jstart; j < jend; ++j) {
                if (cg[b * N_ + j] == ga && j != i) {
                    if (--need == 0) { posj = j; break; }
                }
            }
            if (posj >= 0) {
                const float4* a4 = (const float4*)(coeffs_c + ((size_t)b * N_ + i) * D_);
                const float4* p4 = (const float4*)(coeffs_c + ((size_t)b * N_ + posj) * D_);
                float s0 = 0.f, s1 = 0.f, s2 = 0.f, s3 = 0.f;
                #pragma unroll
                for (int k = 0; k < 8; ++k) {
                    float4 x = a4[k], y = p4[k];
                    s0 = fmaf(x.x, y.x, s0); s1 = fmaf(x.y, y.y, s1);
                    s2 = fmaf(x.z, y.z, s2); s3 = fmaf(x.w, y.w, s3);
                }
                float psim = (s0 + s1) + (s2 + s3);
                // unit vectors: ||a-p||^2 = 2 - 2*a.p  (matches ref to ~1e-6)
                float pos_d = sqrtf(fmaxf(2.f - 2.f * psim, 0.f) + 1e-12f);
                float neg_d = sqrtf(fmaxf(2.f - 2.f * best, 0.f) + 1e-12f);
                contrib = fmaxf(pos_d - neg_d + MARGIN_, 0.0f);
                vflag = 1;
            }
        }
    }

    // block reduction (4 waves)
    float v = contrib;
    int c = vflag;
    #pragma unroll
    for (int off = 32; off > 0; off >>= 1) {
        v += __shfl_down(v, off);
        c += __shfl_down(c, off);
    }
    __shared__ float swv[4];
    __shared__ int swc[4];
    int lane = tid & 63, wv = tid >> 6;
    if (lane == 0) { swv[wv] = v; swc[wv] = c; }
    __syncthreads();
    if (tid == 0) {
        float tv = swv[0] + swv[1] + swv[2] + swv[3];
        int tc = swc[0] + swc[1] + swc[2] + swc[3];
        if (tc > 0 || tv != 0.0f) {
            atomicAdd(&accum[0], tv);
            atomicAdd(((int*)accum) + 1, tc);
        }
    }
}

// ---------------- Kernel 4: finalize ----------------
__global__ void k_final(const float* __restrict__ accum, float* __restrict__ out) {
    float t = accum[0];
    int n = ((const int*)accum)[1];
    out[0] = (n > 0) ? (t / (float)(n > 1 ? n : 1)) : 0.0f;
}

// ---------------- launch ----------------
extern "C" void kernel_launch(void* const* d_in, const int* in_sizes, int n_in,
                              void* d_out, int out_size, void* d_ws, size_t ws_size,
                              hipStream_t stream) {
    const float* pred     = (const float*)d_in[0];
    const float* pos_rand = (const float*)d_in[1];
    const int*   gt       = (const int*)d_in[2];
    const int*   fg       = (const int*)d_in[3];
    float* out = (float*)d_out;

    char* ws = (char*)d_ws;
    // layout (bytes):
    //   coeffs_c : 0         .. 3,276,800   (B*N*D f32, compacted rows)
    //   clist    : 3,276,800 .. 3,379,200   (B*N i32)
    //   cg       : 3,379,200 .. 3,481,600   (B*N i32)
    //   Marr     : 3,481,600 (+64 pad)
    //   p_cnt    : 3,481,664 .. 6,041,664   (B*N*NCH i32)
    //   p_best   : 6,041,664 .. 8,601,664   (B*N*NCH f32)
    //   accum    : 8,601,664 (float total, int ntrip)
    float* coeffs_c = (float*)(ws);
    int*   clist    = (int*)(ws + 3276800);
    int*   cg       = (int*)(ws + 3379200);
    int*   Marr     = (int*)(ws + 3481600);
    int*   p_cnt    = (int*)(ws + 3481664);
    float* p_best   = (float*)(ws + 6041664);
    float* accum    = (float*)(ws + 8601664);

    k_compact<<<B_, 1024, 0, stream>>>(pred, gt, fg, coeffs_c, clist, cg, Marr, accum);
    dim3 gp(NCH, NCH, B_);
    k_pass<<<gp, 256, 0, stream>>>(coeffs_c, cg, Marr, p_cnt, p_best);
    dim3 gc(NCH, B_);
    k_combine<<<gc, 256, 0, stream>>>(coeffs_c, cg, clist, Marr, pos_rand, p_cnt, p_best, accum);
    k_final<<<1, 1, 0, stream>>>(accum, out);
}

// Round 2
// 185.252 us; speedup vs baseline: 1.4719x; 1.4719x over previous
//
#include <hip/hip_runtime.h>
#include <math.h>

// Problem constants (fixed by the reference setup)
#define B_ 4
#define N_ 6400
#define D_ 32
#define TI 512          // anchors per block (2 per thread)
#define TJ 128          // candidate rows per block (LDS-staged)
#define NCHJ 50         // ceil(N_/TJ) — worst-case chunks per batch

static constexpr float MARGIN_ = 0.3f;

// monotone float<->uint map so atomicMax(uint) == float max
__device__ __forceinline__ unsigned fmap(float f) {
    unsigned u = __float_as_uint(f);
    return (u & 0x80000000u) ? ~u : (u | 0x80000000u);
}
__device__ __forceinline__ float funmap(unsigned u) {
    return (u & 0x80000000u) ? __uint_as_float(u ^ 0x80000000u)
                             : __uint_as_float(~u);
}
#define NEG_INF_MAPPED 0x007FFFFFu   // fmap(-inf)

// ---------------- Kernel 1: compaction + init (1 block/batch) ----------------
__global__ __launch_bounds__(1024) void k_compact(const int* __restrict__ gt,
                                                  const int* __restrict__ fg,
                                                  int* __restrict__ clist,
                                                  int* __restrict__ cg,
                                                  int* __restrict__ Marr,
                                                  unsigned* __restrict__ bestArr,
                                                  float* __restrict__ accum) {
    int b = blockIdx.x;
    int tid = threadIdx.x;
    if (b == 0 && tid == 0) { accum[0] = 0.0f; ((int*)accum)[1] = 0; }

    // init per-anchor best (this batch's slice)
    for (int r = tid; r < N_; r += 1024) bestArr[b * N_ + r] = NEG_INF_MAPPED;

    __shared__ int wsum[16];
    __shared__ int sbase;
    if (tid == 0) sbase = 0;
    __syncthreads();

    int lane = tid & 63, wv = tid >> 6;
    for (int t0 = 0; t0 < N_; t0 += 1024) {
        int idx = t0 + tid;
        bool flag = (idx < N_) && (fg[b * N_ + idx] != 0);
        unsigned long long mask = __ballot(flag);
        int lp = __popcll(mask & ((1ull << lane) - 1ull));
        if (lane == 0) wsum[wv] = __popcll(mask);
        __syncthreads();
        int woff = 0, btot = 0;
        #pragma unroll
        for (int w = 0; w < 16; ++w) { if (w < wv) woff += wsum[w]; btot += wsum[w]; }
        int base = sbase;
        if (flag) {
            int pos = base + woff + lp;
            clist[b * N_ + pos] = idx;
            cg[b * N_ + pos] = gt[b * N_ + idx];
        }
        __syncthreads();
        if (tid == 0) sbase = base + btot;
        __syncthreads();
    }
    if (tid == 0) Marr[b] = sbase;
}

// ---------------- Kernel 2: gather + L2-normalize compacted rows ----------------
__global__ __launch_bounds__(256) void k_gather(const float* __restrict__ pred,
                                                const int* __restrict__ clist,
                                                const int* __restrict__ Marr,
                                                float* __restrict__ coeffs_c) {
    int b = blockIdx.y;
    int M = Marr[b];
    int r = blockIdx.x * 256 + threadIdx.x;
    if (r >= M) return;
    int orig = clist[b * N_ + r];
    const float4* s4 = (const float4*)(pred + ((size_t)b * N_ + orig) * D_);
    float4 v[8];
    float ssq = 0.0f;
    #pragma unroll
    for (int k = 0; k < 8; ++k) {
        v[k] = s4[k];
        ssq += v[k].x * v[k].x + v[k].y * v[k].y + v[k].z * v[k].z + v[k].w * v[k].w;
    }
    float inv = 1.0f / fmaxf(sqrtf(ssq), 1e-12f);
    float4* d4 = (float4*)(coeffs_c + ((size_t)b * N_ + r) * D_);
    #pragma unroll
    for (int k = 0; k < 8; ++k) {
        float4 o;
        o.x = v[k].x * inv; o.y = v[k].y * inv; o.z = v[k].z * inv; o.w = v[k].w * inv;
        d4[k] = o;
    }
}

// ---------------- Kernel 3: pair pass (2 anchors/thread) ----------------
// grid = (ceil(N/TI), ceil(N/TJ), B). Per (anchor, j-chunk): same-instance
// count (u8, excl. self) stored per chunk; hardest-negative sim merged via
// atomicMax into per-anchor slot.
__global__ __launch_bounds__(256) void k_pass(const float* __restrict__ coeffs_c,
                                              const int* __restrict__ cg,
                                              const int* __restrict__ Marr,
                                              unsigned char* __restrict__ p_cnt,
                                              unsigned* __restrict__ bestArr) {
    int b = blockIdx.z;
    int M = Marr[b];
    int i0 = blockIdx.x * TI;
    int j0 = blockIdx.y * TJ;
    if (i0 >= M || j0 >= M) return;   // block-uniform exit

    __shared__ float sc[TJ * D_];     // 16 KB
    __shared__ int sg[TJ];
    int tid = threadIdx.x;

    if (tid < TJ) {
        int j = j0 + tid;
        sg[tid] = (j < M) ? cg[b * N_ + j] : -1;
    }
    { // stage rows: thread t -> float4 col (t&7), rows (t>>3)+32k, k<4
        int col = tid & 7;
        int row0 = tid >> 3;
        #pragma unroll
        for (int k = 0; k < 4; ++k) {
            int row = row0 + 32 * k;
            int j = j0 + row;
            float4 val = make_float4(0.f, 0.f, 0.f, 0.f);
            if (j < M) val = ((const float4*)(coeffs_c + ((size_t)b * N_ + j) * D_))[col];
            ((float4*)sc)[row * 8 + col] = val;
        }
    }
    __syncthreads();

    int i1 = i0 + tid;
    int i2 = i0 + 256 + tid;
    bool act1 = (i1 < M);
    bool act2 = (i2 < M);
    if (!act1) return;                // no barriers below; wave-coherent-ish exit

    float4 ca1[8], ca2[8];
    int ga1, ga2 = -2;
    {
        const float4* a4 = (const float4*)(coeffs_c + ((size_t)b * N_ + i1) * D_);
        #pragma unroll
        for (int k = 0; k < 8; ++k) ca1[k] = a4[k];
        ga1 = cg[b * N_ + i1];
    }
    if (act2) {
        const float4* a4 = (const float4*)(coeffs_c + ((size_t)b * N_ + i2) * D_);
        #pragma unroll
        for (int k = 0; k < 8; ++k) ca2[k] = a4[k];
        ga2 = cg[b * N_ + i2];
    } else {
        #pragma unroll
        for (int k = 0; k < 8; ++k) ca2[k] = make_float4(0.f, 0.f, 0.f, 0.f);
    }

    float best1 = -INFINITY, best2 = -INFINITY;
    int cnt1 = 0, cnt2 = 0;
    int jmax = min(TJ, M - j0);
    for (int m = 0; m < jmax; ++m) {
        const float4* cm = (const float4*)(sc + m * D_);
        int g = sg[m];
        float p0 = 0.f, p1 = 0.f, p2 = 0.f, p3 = 0.f;
        float q0 = 0.f, q1 = 0.f, q2 = 0.f, q3 = 0.f;
        #pragma unroll
        for (int k = 0; k < 8; ++k) {
            float4 x = cm[k];
            p0 = fmaf(ca1[k].x, x.x, p0);
            p1 = fmaf(ca1[k].y, x.y, p1);
            p2 = fmaf(ca1[k].z, x.z, p2);
            p3 = fmaf(ca1[k].w, x.w, p3);
            q0 = fmaf(ca2[k].x, x.x, q0);
            q1 = fmaf(ca2[k].y, x.y, q1);
            q2 = fmaf(ca2[k].z, x.z, q2);
            q3 = fmaf(ca2[k].w, x.w, q3);
        }
        float s1 = (p0 + p1) + (p2 + p3);
        float s2 = (q0 + q1) + (q2 + q3);
        int j = j0 + m;
        // all staged rows m < jmax are real fg rows: gt >= 0, so neg == (g != ga)
        bool same1 = (g == ga1);
        bool same2 = (g == ga2);
        if (!same1) best1 = fmaxf(best1, s1);
        if (!same2) best2 = fmaxf(best2, s2);
        cnt1 += (same1 && j != i1) ? 1 : 0;
        cnt2 += (same2 && j != i2) ? 1 : 0;
    }

    int jc = blockIdx.y;
    p_cnt[((size_t)b * N_ + i1) * NCHJ + jc] = (unsigned char)cnt1;
    if (best1 > -INFINITY) atomicMax(&bestArr[b * N_ + i1], fmap(best1));
    if (act2) {
        p_cnt[((size_t)b * N_ + i2) * NCHJ + jc] = (unsigned char)cnt2;
        if (best2 > -INFINITY) atomicMax(&bestArr[b * N_ + i2], fmap(best2));
    }
}

// ---------------- Kernel 4: combine, random positive, hinge ----------------
__global__ __launch_bounds__(256) void k_combine(const float* __restrict__ coeffs_c,
                                                 const int* __restrict__ cg,
                                                 const int* __restrict__ clist,
                                                 const int* __restrict__ Marr,
                                                 const float* __restrict__ pos_rand,
                                                 const unsigned char* __restrict__ p_cnt,
                                                 const unsigned* __restrict__ bestArr,
                                                 float* __restrict__ accum) {
    int b = blockIdx.y;
    int M = Marr[b];
    int i0 = blockIdx.x * 256;
    if (i0 >= M) return;  // block-uniform

    int tid = threadIdx.x;
    int i = i0 + tid;
    float contrib = 0.0f;
    int vflag = 0;

    if (i < M) {
        int nchj = (M + TJ - 1) / TJ;
        const unsigned char* pc = p_cnt + ((size_t)b * N_ + i) * NCHJ;
        int num_pos = 0;
        for (int s = 0; s < nchj; ++s) num_pos += pc[s];
        unsigned bu = bestArr[b * N_ + i];
        bool hasneg = (bu != NEG_INF_MAPPED);
        if (num_pos >= 1 && hasneg) {
            float best = funmap(bu);
            int orig = clist[b * N_ + i];
            float u = pos_rand[b * N_ + orig];
            int pcx = (int)floorf(u * (float)num_pos);   // matches jnp f32 math
            int hi = num_pos - 1;
            pcx = pcx < 0 ? 0 : (pcx > hi ? hi : pcx);
            int target = pcx + 1;
            // locate chunk holding the target-th positive
            int s = 0, c0 = 0;
            for (; s < nchj; ++s) { int c = pc[s]; if (c0 + c >= target) break; c0 += c; }
            int need = target - c0;
            int jstart = s * TJ, jend = min(jstart + TJ, M);
            int ga = cg[b * N_ + i];
            int posj = -1;
            for (int j = jstart; j < jend; ++j) {
                if (cg[b * N_ + j] == ga && j != i) {
                    if (--need == 0) { posj = j; break; }
                }
            }
            if (posj >= 0) {
                const float4* a4 = (const float4*)(coeffs_c + ((size_t)b * N_ + i) * D_);
                const float4* p4 = (const float4*)(coeffs_c + ((size_t)b * N_ + posj) * D_);
                float s0 = 0.f, s1 = 0.f, s2 = 0.f, s3 = 0.f;
                #pragma unroll
                for (int k = 0; k < 8; ++k) {
                    float4 x = a4[k], y = p4[k];
                    s0 = fmaf(x.x, y.x, s0); s1 = fmaf(x.y, y.y, s1);
                    s2 = fmaf(x.z, y.z, s2); s3 = fmaf(x.w, y.w, s3);
                }
                float psim = (s0 + s1) + (s2 + s3);
                // unit vectors: ||a-p||^2 = 2 - 2*a.p (ref-equivalent to ~1e-6)
                float pos_d = sqrtf(fmaxf(2.f - 2.f * psim, 0.f) + 1e-12f);
                float neg_d = sqrtf(fmaxf(2.f - 2.f * best, 0.f) + 1e-12f);
                contrib = fmaxf(pos_d - neg_d + MARGIN_, 0.0f);
                vflag = 1;
            }
        }
    }

    // block reduction (4 waves)
    float v = contrib;
    int c = vflag;
    #pragma unroll
    for (int off = 32; off > 0; off >>= 1) {
        v += __shfl_down(v, off);
        c += __shfl_down(c, off);
    }
    __shared__ float swv[4];
    __shared__ int swc[4];
    int lane = tid & 63, wv = tid >> 6;
    if (lane == 0) { swv[wv] = v; swc[wv] = c; }
    __syncthreads();
    if (tid == 0) {
        float tv = swv[0] + swv[1] + swv[2] + swv[3];
        int tc = swc[0] + swc[1] + swc[2] + swc[3];
        if (tc > 0) {
            atomicAdd(&accum[0], tv);
            atomicAdd(((int*)accum) + 1, tc);
        }
    }
}

// ---------------- Kernel 5: finalize ----------------
__global__ void k_final(const float* __restrict__ accum, float* __restrict__ out) {
    float t = accum[0];
    int n = ((const int*)accum)[1];
    out[0] = (n > 0) ? (t / (float)(n > 1 ? n : 1)) : 0.0f;
}

// ---------------- launch ----------------
extern "C" void kernel_launch(void* const* d_in, const int* in_sizes, int n_in,
                              void* d_out, int out_size, void* d_ws, size_t ws_size,
                              hipStream_t stream) {
    const float* pred     = (const float*)d_in[0];
    const float* pos_rand = (const float*)d_in[1];
    const int*   gt       = (const int*)d_in[2];
    const int*   fg       = (const int*)d_in[3];
    float* out = (float*)d_out;

    char* ws = (char*)d_ws;
    // layout (bytes):
    //   coeffs_c : 0         .. 3,276,800   (B*N*D f32, compacted rows)
    //   clist    : 3,276,800 .. 3,379,200   (B*N i32)
    //   cg       : 3,379,200 .. 3,481,600   (B*N i32)
    //   Marr     : 3,481,600 (+64 pad)
    //   bestArr  : 3,481,664 .. 3,584,064   (B*N u32, mapped float max)
    //   p_cnt    : 3,584,064 .. 4,864,064   (B*N*NCHJ u8)
    //   accum    : 4,864,064 (float total, int ntrip)
    float*         coeffs_c = (float*)(ws);
    int*           clist    = (int*)(ws + 3276800);
    int*           cg       = (int*)(ws + 3379200);
    int*           Marr     = (int*)(ws + 3481600);
    unsigned*      bestArr  = (unsigned*)(ws + 3481664);
    unsigned char* p_cnt    = (unsigned char*)(ws + 3584064);
    float*         accum    = (float*)(ws + 4864064);

    k_compact<<<B_, 1024, 0, stream>>>(gt, fg, clist, cg, Marr, bestArr, accum);
    dim3 gg((N_ + 255) / 256, B_);
    k_gather<<<gg, 256, 0, stream>>>(pred, clist, Marr, coeffs_c);
    dim3 gp((N_ + TI - 1) / TI, (N_ + TJ - 1) / TJ, B_);
    k_pass<<<gp, 256, 0, stream>>>(coeffs_c, cg, Marr, p_cnt, bestArr);
    dim3 gc((N_ + 255) / 256, B_);
    k_combine<<<gc, 256, 0, stream>>>(coeffs_c, cg, clist, Marr, pos_rand, p_cnt, bestArr, accum);
    k_final<<<1, 1, 0, stream>>>(accum, out);
}

// Round 3
// 125.451 us; speedup vs baseline: 2.1736x; 1.4767x over previous
//
#include <hip/hip_runtime.h>
#include <math.h>

// Problem constants (fixed by the reference setup)
#define B_ 4
#define N_ 6400
#define D_ 32
#define TJ 256          // j-chunk staged in LDS
#define NCHJ 25         // N_/TJ
#define TI 128          // anchors per k_pass block (4 waves x 2 i-tiles x 16)
#define CHUNK 256       // compaction chunk
#define NCC 25          // N_/CHUNK

typedef __attribute__((ext_vector_type(4))) float f32x4;
typedef __attribute__((ext_vector_type(8))) short bf16x8;

static constexpr float MARGIN_ = 0.3f;

// monotone float<->uint map so atomicMax(uint) == float max
__device__ __forceinline__ unsigned fmap(float f) {
    unsigned u = __float_as_uint(f);
    return (u & 0x80000000u) ? ~u : (u | 0x80000000u);
}
__device__ __forceinline__ float funmap(unsigned u) {
    return (u & 0x80000000u) ? __uint_as_float(u ^ 0x80000000u)
                             : __uint_as_float(~u);
}
#define NEG_INF_MAPPED 0x007FFFFFu   // fmap(-inf)

// round-to-nearest-even f32 -> bf16 (no NaN concern in this data path)
__device__ __forceinline__ unsigned short f2bf(float f) {
    unsigned u = __float_as_uint(f);
    unsigned r = u + 0x7fffu + ((u >> 16) & 1u);
    return (unsigned short)(r >> 16);
}
__device__ __forceinline__ float bf2f(unsigned short h) {
    return __uint_as_float(((unsigned)h) << 16);
}
// unpack packed pair (elem even in low 16, odd in high 16)
__device__ __forceinline__ void bf2x(unsigned u, float& e0, float& e1) {
    e0 = __uint_as_float(u << 16);
    e1 = __uint_as_float(u & 0xffff0000u);
}

// ---------------- Kernel 1: per-chunk fg counts + init ----------------
__global__ __launch_bounds__(256) void k_count(const int* __restrict__ fg,
                                               int* __restrict__ chunkcnt,
                                               unsigned* __restrict__ bestArr,
                                               float* __restrict__ accum) {
    int c = blockIdx.x, b = blockIdx.y;
    int t = threadIdx.x;
    int idx = c * CHUNK + t;
    if (b == 0 && c == 0 && t == 0) { accum[0] = 0.0f; ((int*)accum)[1] = 0; }
    bestArr[b * N_ + idx] = NEG_INF_MAPPED;
    bool flag = fg[b * N_ + idx] != 0;
    unsigned long long m = __ballot(flag);
    __shared__ int ws[4];
    if ((t & 63) == 0) ws[t >> 6] = __popcll(m);
    __syncthreads();
    if (t == 0) chunkcnt[b * NCC + c] = ws[0] + ws[1] + ws[2] + ws[3];
}

// ---------------- Kernel 2: tiny serial prefix scan (4 x 25 values) ----------------
__global__ void k_scan(const int* __restrict__ chunkcnt,
                       int* __restrict__ offs, int* __restrict__ Marr) {
    int b = threadIdx.x;
    if (b < B_) {
        int acc = 0;
        for (int c = 0; c < NCC; ++c) { offs[b * NCC + c] = acc; acc += chunkcnt[b * NCC + c]; }
        Marr[b] = acc;
    }
}

// ---------------- Kernel 3: scatter + gather + normalize + bf16 hi/lo split ----------------
__global__ __launch_bounds__(256) void k_scatter(const float* __restrict__ pred,
                                                 const int* __restrict__ gt,
                                                 const int* __restrict__ fg,
                                                 const int* __restrict__ offs,
                                                 unsigned short* __restrict__ hi_g,
                                                 unsigned short* __restrict__ lo_g,
                                                 int* __restrict__ clist,
                                                 int* __restrict__ cg) {
    int c = blockIdx.x, b = blockIdx.y;
    int t = threadIdx.x;
    int idx = c * CHUNK + t;
    bool flag = fg[b * N_ + idx] != 0;
    unsigned long long m = __ballot(flag);
    int lane = t & 63, w = t >> 6;
    int lp = __popcll(m & ((1ull << lane) - 1ull));
    __shared__ int ws[4];
    if (lane == 0) ws[w] = __popcll(m);
    __syncthreads();
    int woff = 0;
    #pragma unroll
    for (int k = 0; k < 4; ++k) if (k < w) woff += ws[k];
    if (!flag) return;
    int rank = offs[b * NCC + c] + woff + lp;
    clist[b * N_ + rank] = idx;
    cg[b * N_ + rank] = gt[b * N_ + idx];

    const float4* s4 = (const float4*)(pred + ((size_t)b * N_ + idx) * D_);
    float f[32];
    float ssq = 0.0f;
    #pragma unroll
    for (int k = 0; k < 8; ++k) {
        float4 q = s4[k];
        f[k * 4] = q.x; f[k * 4 + 1] = q.y; f[k * 4 + 2] = q.z; f[k * 4 + 3] = q.w;
        ssq += q.x * q.x + q.y * q.y + q.z * q.z + q.w * q.w;
    }
    float inv = 1.0f / fmaxf(sqrtf(ssq), 1e-12f);
    unsigned hw[16], lw[16];
    #pragma unroll
    for (int k = 0; k < 16; ++k) {
        float x0 = f[2 * k] * inv, x1 = f[2 * k + 1] * inv;
        unsigned short h0 = f2bf(x0), h1 = f2bf(x1);
        unsigned short l0 = f2bf(x0 - bf2f(h0)), l1 = f2bf(x1 - bf2f(h1));
        hw[k] = (unsigned)h0 | ((unsigned)h1 << 16);
        lw[k] = (unsigned)l0 | ((unsigned)l1 << 16);
    }
    uint4* dh = (uint4*)(hi_g + ((size_t)b * N_ + rank) * 32);
    uint4* dl = (uint4*)(lo_g + ((size_t)b * N_ + rank) * 32);
    #pragma unroll
    for (int k = 0; k < 4; ++k) {
        dh[k] = make_uint4(hw[4 * k], hw[4 * k + 1], hw[4 * k + 2], hw[4 * k + 3]);
        dl[k] = make_uint4(lw[4 * k], lw[4 * k + 1], lw[4 * k + 2], lw[4 * k + 3]);
    }
}

// ---------------- Kernel 4: MFMA pair pass ----------------
// grid = (ceil(N/TI), ceil(N/TJ), B). Wave covers 2 i-tiles of 16 anchors.
// S-tile = 16x16 via mfma_f32_16x16x32_bf16, 3 terms (hi*hi + hi*lo + lo*hi).
// Epilogue: per-element mask (gt compare), running max-neg + pos count.
// C/D layout: col = lane&15, row = (lane>>4)*4 + reg  [m89-verified].
// A frag: row m = lane&15, k = (lane>>4)*8 + j  -> 16B load from row, offset 16*quad.
// B frag (B[k][n] = Cj[n][k]): same per-lane pattern from candidate rows.
__global__ __launch_bounds__(256) void k_pass(const unsigned short* __restrict__ hi_g,
                                              const unsigned short* __restrict__ lo_g,
                                              const int* __restrict__ cg,
                                              const int* __restrict__ Marr,
                                              unsigned short* __restrict__ p_cnt,
                                              unsigned* __restrict__ bestArr) {
    int b = blockIdx.z;
    int M = Marr[b];
    int i0 = blockIdx.x * TI;
    int j0 = blockIdx.y * TJ;
    if (i0 >= M || j0 >= M) return;   // block-uniform exit

    // LDS rows padded to 80 B (40 shorts): 16-lane frag reads = 2-way banks (free)
    __shared__ __align__(16) unsigned short sc_hi[TJ * 40];  // 20 KB
    __shared__ __align__(16) unsigned short sc_lo[TJ * 40];  // 20 KB
    __shared__ int sg[TJ];
    int t = threadIdx.x;

    {
        int j = j0 + t;
        sg[t] = (j < M) ? cg[b * N_ + j] : -1;
    }
    {   // stage: thread -> (row = p*64 + t>>2, 16B seg = t&3); fully coalesced global reads
        int seg = t & 3, r0 = t >> 2;
        #pragma unroll
        for (int p = 0; p < 4; ++p) {
            int row = p * 64 + r0;
            int j = j0 + row;
            uint4 vh = make_uint4(0u, 0u, 0u, 0u), vl = make_uint4(0u, 0u, 0u, 0u);
            if (j < M) {
                vh = *(const uint4*)(hi_g + ((size_t)b * N_ + j) * 32 + seg * 8);
                vl = *(const uint4*)(lo_g + ((size_t)b * N_ + j) * 32 + seg * 8);
            }
            *(uint4*)(sc_hi + row * 40 + seg * 8) = vh;
            *(uint4*)(sc_lo + row * 40 + seg * 8) = vl;
        }
    }
    __syncthreads();

    int lane = t & 63, w = t >> 6;
    int r = lane & 15, quad = lane >> 4;
    int ib = i0 + w * 32;            // this wave's 32 anchors (2 i-tiles)

    bf16x8 a_hi[2], a_lo[2];
    int gt_i[2][4];
    #pragma unroll
    for (int it = 0; it < 2; ++it) {
        int i = ib + it * 16 + r;
        bf16x8 zh = {0, 0, 0, 0, 0, 0, 0, 0};
        a_hi[it] = zh; a_lo[it] = zh;
        if (i < M) {
            a_hi[it] = *(const bf16x8*)(hi_g + ((size_t)b * N_ + i) * 32 + quad * 8);
            a_lo[it] = *(const bf16x8*)(lo_g + ((size_t)b * N_ + i) * 32 + quad * 8);
        }
        #pragma unroll
        for (int r4 = 0; r4 < 4; ++r4) {
            int ia = ib + it * 16 + quad * 4 + r4;
            gt_i[it][r4] = (ia < M) ? cg[b * N_ + ia] : -2;
        }
    }

    float best[2][4];
    int cnt[2][4];
    #pragma unroll
    for (int it = 0; it < 2; ++it)
        #pragma unroll
        for (int r4 = 0; r4 < 4; ++r4) { best[it][r4] = -INFINITY; cnt[it][r4] = 0; }

    int jrows = min(TJ, M - j0);
    int ntile = (jrows + 15) >> 4;
    for (int jt = 0; jt < ntile; ++jt) {
        int gtj = sg[jt * 16 + r];
        bf16x8 bh = *(const bf16x8*)(sc_hi + (jt * 16 + r) * 40 + quad * 8);
        bf16x8 bl = *(const bf16x8*)(sc_lo + (jt * 16 + r) * 40 + quad * 8);
        bool jv = (gtj >= 0);
        #pragma unroll
        for (int it = 0; it < 2; ++it) {
            f32x4 acc = {0.f, 0.f, 0.f, 0.f};
            acc = __builtin_amdgcn_mfma_f32_16x16x32_bf16(a_hi[it], bh, acc, 0, 0, 0);
            acc = __builtin_amdgcn_mfma_f32_16x16x32_bf16(a_hi[it], bl, acc, 0, 0, 0);
            acc = __builtin_amdgcn_mfma_f32_16x16x32_bf16(a_lo[it], bh, acc, 0, 0, 0);
            #pragma unroll
            for (int r4 = 0; r4 < 4; ++r4) {
                float s = acc[r4];
                bool same = (gtj == gt_i[it][r4]);
                float sm = (same || !jv) ? -INFINITY : s;
                best[it][r4] = fmaxf(best[it][r4], sm);
                cnt[it][r4] += same ? 1 : 0;   // self-pair included; fixed in combine
            }
        }
    }

    // reduce across the 16 lanes of each col-group (butterfly), then write
    #pragma unroll
    for (int it = 0; it < 2; ++it) {
        #pragma unroll
        for (int r4 = 0; r4 < 4; ++r4) {
            float bb = best[it][r4];
            int cc = cnt[it][r4];
            #pragma unroll
            for (int mk = 1; mk < 16; mk <<= 1) {
                bb = fmaxf(bb, __shfl_xor(bb, mk));
                cc += __shfl_xor(cc, mk);
            }
            if (r == 0) {
                int ia = ib + it * 16 + quad * 4 + r4;
                if (ia < M) {
                    p_cnt[((size_t)b * N_ + ia) * NCHJ + blockIdx.y] = (unsigned short)cc;
                    if (bb > -INFINITY) atomicMax(&bestArr[b * N_ + ia], fmap(bb));
                }
            }
        }
    }
}

// ---------------- Kernel 5: combine, random positive, hinge ----------------
__global__ __launch_bounds__(256) void k_combine(const unsigned short* __restrict__ hi_g,
                                                 const unsigned short* __restrict__ lo_g,
                                                 const int* __restrict__ cg,
                                                 const int* __restrict__ clist,
                                                 const int* __restrict__ Marr,
                                                 const float* __restrict__ pos_rand,
                                                 const unsigned short* __restrict__ p_cnt,
                                                 const unsigned* __restrict__ bestArr,
                                                 float* __restrict__ accum) {
    int b = blockIdx.y;
    int M = Marr[b];
    int i0 = blockIdx.x * 256;
    if (i0 >= M) return;  // block-uniform

    int t = threadIdx.x;
    int i = i0 + t;
    float contrib = 0.0f;
    int vflag = 0;

    if (i < M) {
        int nchj = (M + TJ - 1) / TJ;
        const unsigned short* pc = p_cnt + ((size_t)b * N_ + i) * NCHJ;
        int ich = i / TJ;
        int num_pos = 0;
        for (int s = 0; s < nchj; ++s) num_pos += pc[s];
        num_pos -= 1;   // remove self (always same-instance with itself)
        unsigned bu = bestArr[b * N_ + i];
        if (num_pos >= 1 && bu != NEG_INF_MAPPED) {
            float best = funmap(bu);
            int orig = clist[b * N_ + i];
            float u = pos_rand[b * N_ + orig];
            int pcx = (int)floorf(u * (float)num_pos);   // matches jnp f32 math
            int hi2 = num_pos - 1;
            pcx = pcx < 0 ? 0 : (pcx > hi2 ? hi2 : pcx);
            int target = pcx + 1;
            int s = 0, c0 = 0;
            for (; s < nchj; ++s) {
                int c = (int)pc[s] - (s == ich ? 1 : 0);
                if (c0 + c >= target) break;
                c0 += c;
            }
            int need = target - c0;
            int jstart = s * TJ, jend = min(jstart + TJ, M);
            int ga = cg[b * N_ + i];
            int posj = -1;
            for (int j = jstart; j < jend; j += 4) {   // 4-wide to batch loads
                int g0 = cg[b * N_ + j];
                int g1 = (j + 1 < jend) ? cg[b * N_ + j + 1] : -3;
                int g2 = (j + 2 < jend) ? cg[b * N_ + j + 2] : -3;
                int g3 = (j + 3 < jend) ? cg[b * N_ + j + 3] : -3;
                if (g0 == ga && j != i)     { if (--need == 0) { posj = j;     break; } }
                if (g1 == ga && j + 1 != i) { if (--need == 0) { posj = j + 1; break; } }
                if (g2 == ga && j + 2 != i) { if (--need == 0) { posj = j + 2; break; } }
                if (g3 == ga && j + 3 != i) { if (--need == 0) { posj = j + 3; break; } }
            }
            if (posj >= 0) {
                const uint4* ah = (const uint4*)(hi_g + ((size_t)b * N_ + i) * 32);
                const uint4* al = (const uint4*)(lo_g + ((size_t)b * N_ + i) * 32);
                const uint4* ph = (const uint4*)(hi_g + ((size_t)b * N_ + posj) * 32);
                const uint4* pl = (const uint4*)(lo_g + ((size_t)b * N_ + posj) * 32);
                float dot = 0.0f;
                #pragma unroll
                for (int k = 0; k < 4; ++k) {
                    uint4 xh = ah[k], xl = al[k], yh = ph[k], yl = pl[k];
                    const unsigned hx[4] = {xh.x, xh.y, xh.z, xh.w};
                    const unsigned lx[4] = {xl.x, xl.y, xl.z, xl.w};
                    const unsigned hy[4] = {yh.x, yh.y, yh.z, yh.w};
                    const unsigned ly[4] = {yl.x, yl.y, yl.z, yl.w};
                    #pragma unroll
                    for (int q = 0; q < 4; ++q) {
                        float xe0, xe1, xl0, xl1, ye0, ye1, yl0, yl1;
                        bf2x(hx[q], xe0, xe1); bf2x(lx[q], xl0, xl1);
                        bf2x(hy[q], ye0, ye1); bf2x(ly[q], yl0, yl1);
                        dot = fmaf(xe0 + xl0, ye0 + yl0, dot);
                        dot = fmaf(xe1 + xl1, ye1 + yl1, dot);
                    }
                }
                // unit vectors: ||a-p||^2 = 2 - 2*a.p (ref-equivalent to ~1e-6)
                float pos_d = sqrtf(fmaxf(2.f - 2.f * dot, 0.f) + 1e-12f);
                float neg_d = sqrtf(fmaxf(2.f - 2.f * best, 0.f) + 1e-12f);
                contrib = fmaxf(pos_d - neg_d + MARGIN_, 0.0f);
                vflag = 1;
            }
        }
    }

    // block reduction (4 waves)
    float v = contrib;
    int c = vflag;
    #pragma unroll
    for (int off = 32; off > 0; off >>= 1) {
        v += __shfl_down(v, off);
        c += __shfl_down(c, off);
    }
    __shared__ float swv[4];
    __shared__ int swc[4];
    int lane = t & 63, wv = t >> 6;
    if (lane == 0) { swv[wv] = v; swc[wv] = c; }
    __syncthreads();
    if (t == 0) {
        float tv = swv[0] + swv[1] + swv[2] + swv[3];
        int tc = swc[0] + swc[1] + swc[2] + swc[3];
        if (tc > 0) {
            atomicAdd(&accum[0], tv);
            atomicAdd(((int*)accum) + 1, tc);
        }
    }
}

// ---------------- Kernel 6: finalize ----------------
__global__ void k_final(const float* __restrict__ accum, float* __restrict__ out) {
    float t = accum[0];
    int n = ((const int*)accum)[1];
    out[0] = (n > 0) ? (t / (float)(n > 1 ? n : 1)) : 0.0f;
}

// ---------------- launch ----------------
extern "C" void kernel_launch(void* const* d_in, const int* in_sizes, int n_in,
                              void* d_out, int out_size, void* d_ws, size_t ws_size,
                              hipStream_t stream) {
    const float* pred     = (const float*)d_in[0];
    const float* pos_rand = (const float*)d_in[1];
    const int*   gt       = (const int*)d_in[2];
    const int*   fg       = (const int*)d_in[3];
    float* out = (float*)d_out;

    char* ws = (char*)d_ws;
    // layout (bytes):
    //   hi_g     : 0         .. 1,638,400   (B*N*32 bf16)
    //   lo_g     : 1,638,400 .. 3,276,800
    //   clist    : 3,276,800 .. 3,379,200   (B*N i32)
    //   cg       : 3,379,200 .. 3,481,600   (B*N i32)
    //   Marr     : 3,481,600 .. 3,481,664
    //   chunkcnt : 3,481,664 .. 3,482,176   (100 i32)
    //   offs     : 3,482,176 .. 3,482,688   (100 i32)
    //   bestArr  : 3,482,688 .. 3,585,088   (B*N u32)
    //   p_cnt    : 3,585,088 .. 4,865,088   (B*N*NCHJ u16)
    //   accum    : 4,865,088 (+8)
    unsigned short* hi_g    = (unsigned short*)(ws);
    unsigned short* lo_g    = (unsigned short*)(ws + 1638400);
    int*            clist   = (int*)(ws + 3276800);
    int*            cg      = (int*)(ws + 3379200);
    int*            Marr    = (int*)(ws + 3481600);
    int*            chunkcnt= (int*)(ws + 3481664);
    int*            offs    = (int*)(ws + 3482176);
    unsigned*       bestArr = (unsigned*)(ws + 3482688);
    unsigned short* p_cnt   = (unsigned short*)(ws + 3585088);
    float*          accum   = (float*)(ws + 4865088);

    dim3 gcb(NCC, B_);
    k_count<<<gcb, 256, 0, stream>>>(fg, chunkcnt, bestArr, accum);
    k_scan<<<1, 64, 0, stream>>>(chunkcnt, offs, Marr);
    k_scatter<<<gcb, 256, 0, stream>>>(pred, gt, fg, offs, hi_g, lo_g, clist, cg);
    dim3 gp((N_ + TI - 1) / TI, (N_ + TJ - 1) / TJ, B_);
    k_pass<<<gp, 256, 0, stream>>>(hi_g, lo_g, cg, Marr, p_cnt, bestArr);
    dim3 gc((N_ + 255) / 256, B_);
    k_combine<<<gc, 256, 0, stream>>>(hi_g, lo_g, cg, clist, Marr, pos_rand, p_cnt, bestArr, accum);
    k_final<<<1, 1, 0, stream>>>(accum, out);
}